// Round 6
// baseline (131.721 us; speedup 1.0000x reference)
//
#include <hip/hip_runtime.h>

// Problem: hidden = tanh(x @ (Wi+Wh)^T + (bi+bh)); h_last = hidden[:, -1, :]
// x: (B,T,C) fp32; Wi,Wh: (H,C) fp32. B=16,T=4096,C=H=256.
// GEMM: M=65536, N=256, K=256. Memory-bound: ~64MB read + 67MB write -> ~21us.
//
// v6 (resubmit -- round 5 failed on container acquire, not kernel):
// row-ownership, zero main-loop barriers. Wave owns 16-row stripes; A is
// wave-private (global->reg, no LDS, no sharing). B = full Wc (256x256 bf16,
// 128KB) staged ONCE into static LDS per block (one barrier per block life),
// read via swizzled ds_read_b128. 256 blocks x 512 thr = 1 block/CU; each
// wave: 2 tiles x 8 k-steps = 16 flat steps with a 6-deep rolling register
// prefetch (issue step s+6 while computing s) -> continuous HBM read
// pressure (~5 B/cyc/CU) instead of v2-v5's burst-then-idle phase structure
// (all stalled at ~2 TB/s / 40% HBM duty regardless of sync flavor).

using short8 = __attribute__((ext_vector_type(8))) short;
using f32x4  = __attribute__((ext_vector_type(4))) float;

constexpr int Bn = 16, Tn = 4096, Cn = 256, Hn = 256;
constexpr int Mn   = Bn * Tn;          // 65536
constexpr int NBLK = 256;              // exactly 1 block per CU
constexpr int RPB  = Mn / NBLK;        // 256 rows per block
constexpr int STEPS = 16;              // 2 tiles x 8 k-steps per wave
constexpr int DEPTH = 6;               // prefetch distance (k-steps)

// round-to-nearest-even fp32 -> bf16, two at a time, packed into one u32
__device__ inline unsigned pack2_bf16(float a, float b) {
  unsigned ua = __float_as_uint(a);
  unsigned ub = __float_as_uint(b);
  ua += 0x7fffu + ((ua >> 16) & 1u);
  ub += 0x7fffu + ((ub >> 16) & 1u);
  return (ua >> 16) | (ub & 0xffff0000u);
}

__global__ __launch_bounds__(256) void prep_kernel(
    const float* __restrict__ Wi, const float* __restrict__ bi,
    const float* __restrict__ Wh, const float* __restrict__ bh,
    unsigned short* __restrict__ Wc, float* __restrict__ bc) {
  int idx = blockIdx.x * 256 + threadIdx.x;
  float w = Wi[idx] + Wh[idx];
  unsigned u = __float_as_uint(w);
  u += 0x7fffu + ((u >> 16) & 1u);
  Wc[idx] = (unsigned short)(u >> 16);
  if (blockIdx.x == 0) bc[threadIdx.x] = bi[threadIdx.x] + bh[threadIdx.x];
}

// 512 threads = 8 waves. Wave w, tile j: rows row0 + (j*8+w)*16, ALL 256 cols.
// B LDS: row n (=output col) is 256 bf16; stored as 16B chunks with chunk' =
// chunk ^ (n&7). Read (fixed ks,nt): lanes spread 8-per-4-bank-group,
// balanced -> conflict-free at ds_read_b128 baseline rate.
__global__ __launch_bounds__(512, 2) void gemm_tanh_kernel(
    const float* __restrict__ x, const unsigned short* __restrict__ Wc,
    const float* __restrict__ bc, float* __restrict__ out) {
  __shared__ __align__(16) unsigned short Bs[Hn * Cn];  // 128 KB

  const int tid  = threadIdx.x;
  const int lane = tid & 63;
  const int wave = tid >> 6;        // 0..7
  const int rid  = lane & 15;       // A-row / B-col within 16x16 tile
  const int kgrp = lane >> 4;       // 0..3: k-group of 8
  const int row0 = blockIdx.x * RPB;

  // A source base for this lane; tile j adds j*(8*16) rows, k-step adds 32 f.
  const float* aBase = x + (size_t)(row0 + wave * 16 + rid) * Cn + kgrp * 8;

  // ---- rolling prefetch queue: issue first DEPTH k-steps' A loads now
  float4 xq[8][2];
#pragma unroll
  for (int s = 0; s < DEPTH; s++) {
    const float* p = aBase + (s >> 3) * (8 * 16 * Cn) + (s & 7) * 32;
    xq[s][0] = *(const float4*)p;
    xq[s][1] = *(const float4*)(p + 4);
  }

  // bias for this lane's 16 column slots
  float bias[16];
#pragma unroll
  for (int nt = 0; nt < 16; nt++) bias[nt] = bc[nt * 16 + rid];

  // ---- stage full Wc into LDS (bf16, XOR-swizzled 16B chunks); one barrier
#pragma unroll
  for (int i = 0; i < 16; i++) {
    int g = i * 512 + tid;          // 16B-chunk id, 8192 total
    int n = g >> 5;                 // B row (output col) 0..255
    int c = g & 31;                 // chunk within row
    uint4 v = *(const uint4*)(Wc + n * Cn + c * 8);
    *(uint4*)&Bs[n * Cn + ((c ^ (n & 7)) << 3)] = v;
  }
  __syncthreads();

  f32x4 acc[16];
#pragma unroll
  for (int nt = 0; nt < 16; nt++) acc[nt] = (f32x4)0.f;

#pragma unroll
  for (int s = 0; s < STEPS; s++) {
    // convert step s's 8 floats -> bf16 A-fragment
    union { unsigned u[4]; short8 v; } cv;
    float4 a0 = xq[s & 7][0], a1 = xq[s & 7][1];
    cv.u[0] = pack2_bf16(a0.x, a0.y);
    cv.u[1] = pack2_bf16(a0.z, a0.w);
    cv.u[2] = pack2_bf16(a1.x, a1.y);
    cv.u[3] = pack2_bf16(a1.z, a1.w);
    short8 af = cv.v;

    // keep the read stream fed: issue loads for step s+DEPTH
    if (s + DEPTH < STEPS) {
      const int s2 = s + DEPTH;
      const float* p = aBase + (s2 >> 3) * (8 * 16 * Cn) + (s2 & 7) * 32;
      xq[s2 & 7][0] = *(const float4*)p;
      xq[s2 & 7][1] = *(const float4*)(p + 4);
    }

    // B from LDS + 16 MFMAs (one per 16-col tile)
    const int ks = s & 7;
    const int cs = ((((ks << 2) | kgrp) ^ (rid & 7)) << 3);
#pragma unroll
    for (int nt = 0; nt < 16; nt++) {
      short8 bfr = *(const short8*)&Bs[(nt * 16 + rid) * Cn + cs];
      acc[nt] = __builtin_amdgcn_mfma_f32_16x16x32_bf16(af, bfr, acc[nt],
                                                        0, 0, 0);
    }

    // tile boundary: bias + tanh + store (overlaps next tile's in-flight loads)
    if ((s & 7) == 7) {
      const int j = s >> 3;
      const int mrow = row0 + (j * 8 + wave) * 16 + kgrp * 4;
#pragma unroll
      for (int nt = 0; nt < 16; nt++) {
        const int n = nt * 16 + rid;
#pragma unroll
        for (int r = 0; r < 4; r++) {
          const int m = mrow + r;
          float v = acc[nt][r] + bias[nt];
          // tanh(v) = 1 - 2/(exp(2v)+1); overflow -> 1, underflow -> -1
          float tv = 1.f - 2.f / (__expf(2.f * v) + 1.f);
          out[(size_t)m * Hn + n] = tv;
          if ((m & (Tn - 1)) == (Tn - 1))
            out[(size_t)Mn * Hn + (size_t)(m >> 12) * Hn + n] = tv;
          acc[nt][r] = 0.f;
        }
      }
    }
  }
}

extern "C" void kernel_launch(void* const* d_in, const int* in_sizes, int n_in,
                              void* d_out, int out_size, void* d_ws,
                              size_t ws_size, hipStream_t stream) {
  (void)in_sizes; (void)n_in; (void)out_size; (void)ws_size;
  const float* x  = (const float*)d_in[0];
  const float* Wi = (const float*)d_in[1];
  const float* bi = (const float*)d_in[2];
  const float* Wh = (const float*)d_in[3];
  const float* bh = (const float*)d_in[4];
  float* out = (float*)d_out;

  unsigned short* Wc = (unsigned short*)d_ws;  // 128 KB bf16
  float* bc = (float*)((char*)d_ws + (size_t)Hn * Cn * sizeof(unsigned short));

  prep_kernel<<<(Hn * Cn) / 256, 256, 0, stream>>>(Wi, bi, Wh, bh, Wc, bc);
  gemm_tanh_kernel<<<NBLK, 512, 0, stream>>>(x, Wc, bc, out);
}